// Round 14
// baseline (608.778 us; speedup 1.0000x reference)
//
#include <hip/hip_runtime.h>
#include <hip/hip_fp16.h>

#define N_NODES 50000
#define N_EDGES 800000
#define D 64

#define NBIN 512                    // dst bins; bin = d / BINW (50176 slots >= 50000)
#define BINW 98                     // nodes per bin
#define PBLK 160                    // partition blocks
#define EPB  5000                   // edges per part block (160*5000 = 800000)
#define CAPB 26                     // entries per (part-block, bin): mean 9.77, proven r6-r13
#define NCAP 64                     // per-node slots; deg ~ Pois(16), P(>=64) ~ 1e-15
#define WGROUP 260                  // floats per k-group; 260 mod 32 = 4 -> 2-way writes (free)

typedef int iv4 __attribute__((ext_vector_type(4)));

// -------- pass A: partition edges + convert x -> fp16 (UNCHANGED, passing) --
// Lessons held: global atomics = memory-side RMW ~40us/800k (r0/1/2/5);
// per-edge LDS wave-ops ~270cy/edge (r3/6); coop-launch broken under graph
// capture (r10); fp16 gather copy halves beyond-L2 bytes (r11, verified).
__global__ __launch_bounds__(512) void gin_part(const float* __restrict__ x,
                                                const int* __restrict__ src,
                                                const int* __restrict__ dst,
                                                unsigned int* __restrict__ regions,
                                                int* __restrict__ bincnt,
                                                __half* __restrict__ xh) {
    __shared__ int lcnt[NBIN];
    const int tid = threadIdx.x;
    if (tid < NBIN) lcnt[tid] = 0;
    __syncthreads();

    const int ebase = blockIdx.x * EPB;
    unsigned int* __restrict__ rbase = regions + (size_t)blockIdx.x * NBIN * CAPB;

    for (int i = tid; i < EPB / 4; i += 512) {
        const int e = ebase + i * 4;                  // 16B-aligned
        const iv4 d4 = *(const iv4*)&dst[e];
        const iv4 s4 = *(const iv4*)&src[e];
        const int dd[4] = {d4.x, d4.y, d4.z, d4.w};
        const int ss[4] = {s4.x, s4.y, s4.z, s4.w};
        #pragma unroll
        for (int j = 0; j < 4; ++j) {
            const int bin = dd[j] / BINW;             // const-div -> mul/shift
            const int pos = atomicAdd(&lcnt[bin], 1); // divergent lanes -> 64 edges/wave-op
            if (pos < CAPB)
                rbase[bin * CAPB + pos] = ((unsigned)dd[j] << 16) | (unsigned)ss[j];
        }
    }
    __syncthreads();
    if (tid < NBIN) bincnt[blockIdx.x * NBIN + tid] = lcnt[tid] < CAPB ? lcnt[tid] : CAPB;

    // ---- x -> fp16 copy (consumed by the NEXT kernel; no sync needed) ------
    union Pk { uint2 u; __half2 h[2]; };
    uint2* __restrict__ xo = (uint2*)xh;
    for (int i = blockIdx.x * 512 + tid; i < (N_NODES * D) / 4; i += PBLK * 512) {
        const float4 v = *(const float4*)&x[(size_t)i * 4];
        Pk p;
        p.h[0] = __floats2half2_rn(v.x, v.y);
        p.h[1] = __floats2half2_rn(v.z, v.w);
        xo[i] = p.u;
    }
}

// fast tanh: 1 - 2/(e^{2x}+1); __expf saturates correctly at +-inf
__device__ __forceinline__ float fast_tanh(float v) {
    return 1.0f - 2.0f / (__expf(2.0f * v) + 1.0f);
}

// -------- pass B: place + 8-deep fp16 gather + batched MLP ------------------
// ROUND-14 CHANGE: r13's budget shows the MLP is now the larger half of the
// kernel (~660 of ~1200 wave-instrs): 16 full-divergent ds_read_b128 of Wt2
// PER NODE (1024 B of LDS occupancy each, re-read for all 50k nodes). Hoist
// the kg loop over the 4-node batch: one heavy W read now serves 4 nodes
// (heavy LDS wave-ops 16/node -> 4/node; hv reads are cheap broadcasts).
// Accumulators are 4 named float4 (static indexing, rule: no runtime-indexed
// reg arrays). Gather path byte-identical to r13 (passing, ~41 us).
__global__ __launch_bounds__(1024, 8) void gin_node(const float* __restrict__ x,
                                                 const __half* __restrict__ xh,
                                                 const float* __restrict__ W,
                                                 const float* __restrict__ bias,
                                                 const unsigned int* __restrict__ regions,
                                                 const int* __restrict__ bincnt,
                                                 float* __restrict__ out) {
    __shared__ alignas(16) unsigned short sbuck[BINW * NCAP];  // 12544 B per-node slots
    __shared__ int   lcnt[BINW];                               //   392 B per-node degree
    __shared__ float Wt2[16 * WGROUP];                         // 16640 B k-group-major W
    __shared__ float hs[16][4][68];                            // 17408 B per-wave h rows

    const int tid  = threadIdx.x;
    const int lane = tid & 63;           // 0..63
    const int wv   = tid >> 6;           // 0..15
    const int sub  = lane >> 4;          // node group 0..3
    const int q    = lane & 15;          // uint2 slot within fp16 row
    const int b    = blockIdx.x;
    const int lo   = b * BINW;

    if (tid < BINW) lcnt[tid] = 0;
    // stage W: Wt2[g*WGROUP + f*4 + (k&3)] = W[f][k], g = k>>2 (2-way writes, free)
    #pragma unroll
    for (int i = tid; i < D * D; i += 1024) {
        const int f = i >> 6, k = i & 63;
        Wt2[(k >> 2) * WGROUP + (f << 2) + (k & 3)] = W[i];
    }
    __syncthreads();

    // ---- phase 1: place (single list). 2 region-lists per wave-op ----------
    const int g2 = lane >> 5;            // 0..1
    const int l2 = lane & 31;
    for (int p2 = wv; p2 < PBLK / 2; p2 += 16) {
        const int pb = p2 * 2 + g2;
        const int n = bincnt[pb * NBIN + b];         // uniform per 32-group
        if (l2 < n) {                                // n <= CAPB=26 < 32
            const unsigned e = regions[((size_t)pb * NBIN + b) * CAPB + l2];
            const int dl  = (int)(e >> 16) - lo;     // 0..97 by bin construction
            const int pos = atomicAdd(&lcnt[dl], 1); // divergent LDS atomic
            if (pos < NCAP) sbuck[dl * NCAP + pos] = (unsigned short)(e & 0xffffu);
        }
    }
    __syncthreads();

    // ---- phase 2: gather (4 nodes/wave, 8 rows in flight per group) + MLP --
    const uint2* __restrict__ xr = (const uint2*)xh;   // fp16 row = 16 uint2
    const float bf = bias[lane];
    const int ncnt   = (wv < 2) ? 7 : 6;               // 98 = 2*7 + 14*6
    const int nstart = wv * 6 + ((wv < 2) ? wv : 2);
    const int nend   = nstart + ncnt;

    union Pk { uint2 u; __half2 h[2]; };

    for (int base = nstart; base < nend; base += 4) {
        const int li    = base + sub;
        const bool nv   = (li < nend);
        const int  liC  = nv ? li : (nend - 1);      // clamp: safe LDS addr
        const int  node = lo + liC;
        const bool ndv  = nv && (node < N_NODES);    // tail bins 510/511
        const int  nodeC = (node < N_NODES) ? node : (N_NODES - 1);

        // self row fp32 (exact (1+eps)*x_n term)
        float4 acc = *(const float4*)&x[(size_t)nodeC * D + (q << 2)];

        int cn = ndv ? lcnt[liC] : 0;
        if (cn > NCAP) cn = NCAP;
        const uint4* __restrict__ slv = (const uint4*)&sbuck[liC * NCAP];

        for (int i = 0; i < cn; i += 8) {            // divergent per group: exec-masked
            const int rem = cn - i;                  // uniform within group
            // ONE broadcast b128 read: 8 u16 indices (row 128B-aligned, i%8==0)
            const uint4 iw = slv[i >> 3];
            int s0 = (int)(iw.x & 0xffffu), s1 = (int)(iw.x >> 16);
            int s2 = (int)(iw.y & 0xffffu), s3 = (int)(iw.y >> 16);
            int s4 = (int)(iw.z & 0xffffu), s5 = (int)(iw.z >> 16);
            int s6 = (int)(iw.w & 0xffffu), s7 = (int)(iw.w >> 16);
            // sanitize BEFORE address calc (unwritten slots hold garbage u16)
            s1 = (1 < rem) ? s1 : 0;  s2 = (2 < rem) ? s2 : 0;
            s3 = (3 < rem) ? s3 : 0;  s4 = (4 < rem) ? s4 : 0;
            s5 = (5 < rem) ? s5 : 0;  s6 = (6 < rem) ? s6 : 0;
            s7 = (7 < rem) ? s7 : 0;
            // 8 fp16 row loads in flight (8 B/lane; each instr covers 4 nodes)
            Pk u0, u1, u2, u3, u4, u5, u6, u7;
            u0.u = xr[(size_t)s0 * 16 + q];  u1.u = xr[(size_t)s1 * 16 + q];
            u2.u = xr[(size_t)s2 * 16 + q];  u3.u = xr[(size_t)s3 * 16 + q];
            u4.u = xr[(size_t)s4 * 16 + q];  u5.u = xr[(size_t)s5 * 16 + q];
            u6.u = xr[(size_t)s6 * 16 + q];  u7.u = xr[(size_t)s7 * 16 + q];
            const float m1 = (1 < rem) ? 1.f : 0.f;  // edge 0 valid when loop entered
            const float m2 = (2 < rem) ? 1.f : 0.f;
            const float m3 = (3 < rem) ? 1.f : 0.f;
            const float m4 = (4 < rem) ? 1.f : 0.f;
            const float m5 = (5 < rem) ? 1.f : 0.f;
            const float m6 = (6 < rem) ? 1.f : 0.f;
            const float m7 = (7 < rem) ? 1.f : 0.f;
            {
                const float2 a = __half22float2(u0.h[0]), c = __half22float2(u0.h[1]);
                acc.x += a.x; acc.y += a.y; acc.z += c.x; acc.w += c.y;
            }
            {
                const float2 a = __half22float2(u1.h[0]), c = __half22float2(u1.h[1]);
                acc.x = fmaf(a.x, m1, acc.x); acc.y = fmaf(a.y, m1, acc.y);
                acc.z = fmaf(c.x, m1, acc.z); acc.w = fmaf(c.y, m1, acc.w);
            }
            {
                const float2 a = __half22float2(u2.h[0]), c = __half22float2(u2.h[1]);
                acc.x = fmaf(a.x, m2, acc.x); acc.y = fmaf(a.y, m2, acc.y);
                acc.z = fmaf(c.x, m2, acc.z); acc.w = fmaf(c.y, m2, acc.w);
            }
            {
                const float2 a = __half22float2(u3.h[0]), c = __half22float2(u3.h[1]);
                acc.x = fmaf(a.x, m3, acc.x); acc.y = fmaf(a.y, m3, acc.y);
                acc.z = fmaf(c.x, m3, acc.z); acc.w = fmaf(c.y, m3, acc.w);
            }
            {
                const float2 a = __half22float2(u4.h[0]), c = __half22float2(u4.h[1]);
                acc.x = fmaf(a.x, m4, acc.x); acc.y = fmaf(a.y, m4, acc.y);
                acc.z = fmaf(c.x, m4, acc.z); acc.w = fmaf(c.y, m4, acc.w);
            }
            {
                const float2 a = __half22float2(u5.h[0]), c = __half22float2(u5.h[1]);
                acc.x = fmaf(a.x, m5, acc.x); acc.y = fmaf(a.y, m5, acc.y);
                acc.z = fmaf(c.x, m5, acc.z); acc.w = fmaf(c.y, m5, acc.w);
            }
            {
                const float2 a = __half22float2(u6.h[0]), c = __half22float2(u6.h[1]);
                acc.x = fmaf(a.x, m6, acc.x); acc.y = fmaf(a.y, m6, acc.y);
                acc.z = fmaf(c.x, m6, acc.z); acc.w = fmaf(c.y, m6, acc.w);
            }
            {
                const float2 a = __half22float2(u7.h[0]), c = __half22float2(u7.h[1]);
                acc.x = fmaf(a.x, m7, acc.x); acc.y = fmaf(a.y, m7, acc.y);
                acc.z = fmaf(c.x, m7, acc.z); acc.w = fmaf(c.y, m7, acc.w);
            }
        }
        // stash h row (one ds_write_b128 per group)
        *(float4*)&hs[wv][sub][q << 2] = acc;

        // ---- MLP, batched: ONE heavy W read per kg serves all 4 nodes ------
        // (hv reads are same-address broadcasts: cheap). Junk hs slots of
        // clamped nodes are computed but never stored. Named accumulators
        // only (no runtime-indexed register arrays).
        float4 rA = {bf, 0.f, 0.f, 0.f};
        float4 rB = rA, rC = rA, rD = rA;
        #pragma unroll
        for (int kg = 0; kg < 16; ++kg) {
            const float4 w  = *(const float4*)&Wt2[kg * WGROUP + (lane << 2)];
            const float4 hA = *(const float4*)&hs[wv][0][kg << 2];  // broadcast
            const float4 hB = *(const float4*)&hs[wv][1][kg << 2];
            const float4 hC = *(const float4*)&hs[wv][2][kg << 2];
            const float4 hD = *(const float4*)&hs[wv][3][kg << 2];
            rA.x = fmaf(hA.x, w.x, rA.x); rA.y = fmaf(hA.y, w.y, rA.y);
            rA.z = fmaf(hA.z, w.z, rA.z); rA.w = fmaf(hA.w, w.w, rA.w);
            rB.x = fmaf(hB.x, w.x, rB.x); rB.y = fmaf(hB.y, w.y, rB.y);
            rB.z = fmaf(hB.z, w.z, rB.z); rB.w = fmaf(hB.w, w.w, rB.w);
            rC.x = fmaf(hC.x, w.x, rC.x); rC.y = fmaf(hC.y, w.y, rC.y);
            rC.z = fmaf(hC.z, w.z, rC.z); rC.w = fmaf(hC.w, w.w, rC.w);
            rD.x = fmaf(hD.x, w.x, rD.x); rD.y = fmaf(hD.y, w.y, rD.y);
            rD.z = fmaf(hD.z, w.z, rD.z); rD.w = fmaf(hD.w, w.w, rD.w);
        }
        const int left = nend - base;
        const int mcnt = left < 4 ? left : 4;
        const int n0 = lo + base;
        if (n0 < N_NODES)
            out[(size_t)n0 * D + lane] = fast_tanh((rA.x + rA.y) + (rA.z + rA.w));
        if (1 < mcnt && n0 + 1 < N_NODES)
            out[(size_t)(n0 + 1) * D + lane] = fast_tanh((rB.x + rB.y) + (rB.z + rB.w));
        if (2 < mcnt && n0 + 2 < N_NODES)
            out[(size_t)(n0 + 2) * D + lane] = fast_tanh((rC.x + rC.y) + (rC.z + rC.w));
        if (3 < mcnt && n0 + 3 < N_NODES)
            out[(size_t)(n0 + 3) * D + lane] = fast_tanh((rD.x + rD.y) + (rD.z + rD.w));
    }
}

extern "C" void kernel_launch(void* const* d_in, const int* in_sizes, int n_in,
                              void* d_out, int out_size, void* d_ws, size_t ws_size,
                              hipStream_t stream) {
    const float* x    = (const float*)d_in[0];   // [N, 64]
    const float* W    = (const float*)d_in[1];   // [64, 64] (PyTorch [out,in])
    const float* bias = (const float*)d_in[2];   // [64]
    const int*   src  = (const int*)d_in[3];     // [E] (int32 on device)
    const int*   dst  = (const int*)d_in[4];     // [E]
    float*       out  = (float*)d_out;           // [N, 64]

    // workspace: regions [160][512][26] u32 (8.52 MB) + bincnt [160][512]
    // (328 KB) + xh [N][64] fp16 (6.4 MB) = 15.3 MB. Nothing pre-cleared.
    unsigned int* regions = (unsigned int*)d_ws;
    int*          bincnt  = (int*)(regions + (size_t)PBLK * NBIN * CAPB);
    __half*       xh      = (__half*)(bincnt + PBLK * NBIN);

    gin_part<<<PBLK, 512, 0, stream>>>(x, src, dst, regions, bincnt, xh);
    gin_node<<<NBIN, 1024, 0, stream>>>(x, xh, W, bias, regions, bincnt, out);
}

// Round 15
// 109.394 us; speedup vs baseline: 5.5650x; 5.5650x over previous
//
#include <hip/hip_runtime.h>
#include <hip/hip_fp16.h>

#define N_NODES 50000
#define N_EDGES 800000
#define D 64

#define NBIN 512                    // dst bins; bin = d / BINW (50176 slots >= 50000)
#define BINW 98                     // nodes per bin
#define PBLK 160                    // partition blocks
#define EPB  5000                   // edges per part block (160*5000 = 800000)
#define CAPB 26                     // entries per (part-block, bin): mean 9.77, proven r6-r13
#define NCAP 64                     // per-node slots; deg ~ Pois(16), P(>=64) ~ 1e-15
#define WGROUP 260                  // floats per k-group; 260 mod 32 = 4 -> 2-way writes (free)

typedef int iv4 __attribute__((ext_vector_type(4)));

// -------- pass A: partition edges + convert x -> fp16 (UNCHANGED, passing) --
// Lessons held: global atomics = memory-side RMW ~40us/800k (r0/1/2/5);
// per-edge LDS wave-ops ~270cy/edge (r3/6); coop-launch broken under graph
// capture (r10); fp16 gather copy halves beyond-L2 bytes (r11, verified);
// 64-VGPR cap + wide batch + full unroll = scratch spill catastrophe (r14).
__global__ __launch_bounds__(512) void gin_part(const float* __restrict__ x,
                                                const int* __restrict__ src,
                                                const int* __restrict__ dst,
                                                unsigned int* __restrict__ regions,
                                                int* __restrict__ bincnt,
                                                __half* __restrict__ xh) {
    __shared__ int lcnt[NBIN];
    const int tid = threadIdx.x;
    if (tid < NBIN) lcnt[tid] = 0;
    __syncthreads();

    const int ebase = blockIdx.x * EPB;
    unsigned int* __restrict__ rbase = regions + (size_t)blockIdx.x * NBIN * CAPB;

    for (int i = tid; i < EPB / 4; i += 512) {
        const int e = ebase + i * 4;                  // 16B-aligned
        const iv4 d4 = *(const iv4*)&dst[e];
        const iv4 s4 = *(const iv4*)&src[e];
        const int dd[4] = {d4.x, d4.y, d4.z, d4.w};
        const int ss[4] = {s4.x, s4.y, s4.z, s4.w};
        #pragma unroll
        for (int j = 0; j < 4; ++j) {
            const int bin = dd[j] / BINW;             // const-div -> mul/shift
            const int pos = atomicAdd(&lcnt[bin], 1); // divergent lanes -> 64 edges/wave-op
            if (pos < CAPB)
                rbase[bin * CAPB + pos] = ((unsigned)dd[j] << 16) | (unsigned)ss[j];
        }
    }
    __syncthreads();
    if (tid < NBIN) bincnt[blockIdx.x * NBIN + tid] = lcnt[tid] < CAPB ? lcnt[tid] : CAPB;

    // ---- x -> fp16 copy (consumed by the NEXT kernel; no sync needed) ------
    union Pk { uint2 u; __half2 h[2]; };
    uint2* __restrict__ xo = (uint2*)xh;
    for (int i = blockIdx.x * 512 + tid; i < (N_NODES * D) / 4; i += PBLK * 512) {
        const float4 v = *(const float4*)&x[(size_t)i * 4];
        Pk p;
        p.h[0] = __floats2half2_rn(v.x, v.y);
        p.h[1] = __floats2half2_rn(v.z, v.w);
        xo[i] = p.u;
    }
}

// fast tanh: 1 - 2/(e^{2x}+1); __expf saturates correctly at +-inf
__device__ __forceinline__ float fast_tanh(float v) {
    return 1.0f - 2.0f / (__expf(2.0f * v) + 1.0f);
}

// -------- pass B: place + 8-deep fp16 gather + pair-batched MLP -------------
// ROUND-15 CHANGE: r14's 4-node-batched MLP (+16 accum VGPRs, full unroll)
// spilled to scratch under the 64-VGPR cap (FETCH 45->802 MB, 5x slower).
// Same amortization at survivable cost: batch W reads over PAIRS of nodes
// (+8 VGPRs; heavy divergent W reads 16/node -> 8/node) and cap the kg loop
// at unroll 4 so the scheduler can't pipeline 16 iterations of loads.
// Gather path byte-identical to r13 (passing, ~41 us).
__global__ __launch_bounds__(1024, 8) void gin_node(const float* __restrict__ x,
                                                 const __half* __restrict__ xh,
                                                 const float* __restrict__ W,
                                                 const float* __restrict__ bias,
                                                 const unsigned int* __restrict__ regions,
                                                 const int* __restrict__ bincnt,
                                                 float* __restrict__ out) {
    __shared__ alignas(16) unsigned short sbuck[BINW * NCAP];  // 12544 B per-node slots
    __shared__ int   lcnt[BINW];                               //   392 B per-node degree
    __shared__ float Wt2[16 * WGROUP];                         // 16640 B k-group-major W
    __shared__ float hs[16][4][68];                            // 17408 B per-wave h rows

    const int tid  = threadIdx.x;
    const int lane = tid & 63;           // 0..63
    const int wv   = tid >> 6;           // 0..15
    const int sub  = lane >> 4;          // node group 0..3
    const int q    = lane & 15;          // uint2 slot within fp16 row
    const int b    = blockIdx.x;
    const int lo   = b * BINW;

    if (tid < BINW) lcnt[tid] = 0;
    // stage W: Wt2[g*WGROUP + f*4 + (k&3)] = W[f][k], g = k>>2 (2-way writes, free)
    #pragma unroll
    for (int i = tid; i < D * D; i += 1024) {
        const int f = i >> 6, k = i & 63;
        Wt2[(k >> 2) * WGROUP + (f << 2) + (k & 3)] = W[i];
    }
    __syncthreads();

    // ---- phase 1: place (single list). 2 region-lists per wave-op ----------
    const int g2 = lane >> 5;            // 0..1
    const int l2 = lane & 31;
    for (int p2 = wv; p2 < PBLK / 2; p2 += 16) {
        const int pb = p2 * 2 + g2;
        const int n = bincnt[pb * NBIN + b];         // uniform per 32-group
        if (l2 < n) {                                // n <= CAPB=26 < 32
            const unsigned e = regions[((size_t)pb * NBIN + b) * CAPB + l2];
            const int dl  = (int)(e >> 16) - lo;     // 0..97 by bin construction
            const int pos = atomicAdd(&lcnt[dl], 1); // divergent LDS atomic
            if (pos < NCAP) sbuck[dl * NCAP + pos] = (unsigned short)(e & 0xffffu);
        }
    }
    __syncthreads();

    // ---- phase 2: gather (4 nodes/wave, 8 rows in flight per group) + MLP --
    const uint2* __restrict__ xr = (const uint2*)xh;   // fp16 row = 16 uint2
    const float bf = bias[lane];
    const int ncnt   = (wv < 2) ? 7 : 6;               // 98 = 2*7 + 14*6
    const int nstart = wv * 6 + ((wv < 2) ? wv : 2);
    const int nend   = nstart + ncnt;

    union Pk { uint2 u; __half2 h[2]; };

    for (int base = nstart; base < nend; base += 4) {
        const int li    = base + sub;
        const bool nv   = (li < nend);
        const int  liC  = nv ? li : (nend - 1);      // clamp: safe LDS addr
        const int  node = lo + liC;
        const bool ndv  = nv && (node < N_NODES);    // tail bins 510/511
        const int  nodeC = (node < N_NODES) ? node : (N_NODES - 1);

        // self row fp32 (exact (1+eps)*x_n term)
        float4 acc = *(const float4*)&x[(size_t)nodeC * D + (q << 2)];

        int cn = ndv ? lcnt[liC] : 0;
        if (cn > NCAP) cn = NCAP;
        const uint4* __restrict__ slv = (const uint4*)&sbuck[liC * NCAP];

        for (int i = 0; i < cn; i += 8) {            // divergent per group: exec-masked
            const int rem = cn - i;                  // uniform within group
            // ONE broadcast b128 read: 8 u16 indices (row 128B-aligned, i%8==0)
            const uint4 iw = slv[i >> 3];
            int s0 = (int)(iw.x & 0xffffu), s1 = (int)(iw.x >> 16);
            int s2 = (int)(iw.y & 0xffffu), s3 = (int)(iw.y >> 16);
            int s4 = (int)(iw.z & 0xffffu), s5 = (int)(iw.z >> 16);
            int s6 = (int)(iw.w & 0xffffu), s7 = (int)(iw.w >> 16);
            // sanitize BEFORE address calc (unwritten slots hold garbage u16)
            s1 = (1 < rem) ? s1 : 0;  s2 = (2 < rem) ? s2 : 0;
            s3 = (3 < rem) ? s3 : 0;  s4 = (4 < rem) ? s4 : 0;
            s5 = (5 < rem) ? s5 : 0;  s6 = (6 < rem) ? s6 : 0;
            s7 = (7 < rem) ? s7 : 0;
            // 8 fp16 row loads in flight (8 B/lane; each instr covers 4 nodes)
            Pk u0, u1, u2, u3, u4, u5, u6, u7;
            u0.u = xr[(size_t)s0 * 16 + q];  u1.u = xr[(size_t)s1 * 16 + q];
            u2.u = xr[(size_t)s2 * 16 + q];  u3.u = xr[(size_t)s3 * 16 + q];
            u4.u = xr[(size_t)s4 * 16 + q];  u5.u = xr[(size_t)s5 * 16 + q];
            u6.u = xr[(size_t)s6 * 16 + q];  u7.u = xr[(size_t)s7 * 16 + q];
            const float m1 = (1 < rem) ? 1.f : 0.f;  // edge 0 valid when loop entered
            const float m2 = (2 < rem) ? 1.f : 0.f;
            const float m3 = (3 < rem) ? 1.f : 0.f;
            const float m4 = (4 < rem) ? 1.f : 0.f;
            const float m5 = (5 < rem) ? 1.f : 0.f;
            const float m6 = (6 < rem) ? 1.f : 0.f;
            const float m7 = (7 < rem) ? 1.f : 0.f;
            {
                const float2 a = __half22float2(u0.h[0]), c = __half22float2(u0.h[1]);
                acc.x += a.x; acc.y += a.y; acc.z += c.x; acc.w += c.y;
            }
            {
                const float2 a = __half22float2(u1.h[0]), c = __half22float2(u1.h[1]);
                acc.x = fmaf(a.x, m1, acc.x); acc.y = fmaf(a.y, m1, acc.y);
                acc.z = fmaf(c.x, m1, acc.z); acc.w = fmaf(c.y, m1, acc.w);
            }
            {
                const float2 a = __half22float2(u2.h[0]), c = __half22float2(u2.h[1]);
                acc.x = fmaf(a.x, m2, acc.x); acc.y = fmaf(a.y, m2, acc.y);
                acc.z = fmaf(c.x, m2, acc.z); acc.w = fmaf(c.y, m2, acc.w);
            }
            {
                const float2 a = __half22float2(u3.h[0]), c = __half22float2(u3.h[1]);
                acc.x = fmaf(a.x, m3, acc.x); acc.y = fmaf(a.y, m3, acc.y);
                acc.z = fmaf(c.x, m3, acc.z); acc.w = fmaf(c.y, m3, acc.w);
            }
            {
                const float2 a = __half22float2(u4.h[0]), c = __half22float2(u4.h[1]);
                acc.x = fmaf(a.x, m4, acc.x); acc.y = fmaf(a.y, m4, acc.y);
                acc.z = fmaf(c.x, m4, acc.z); acc.w = fmaf(c.y, m4, acc.w);
            }
            {
                const float2 a = __half22float2(u5.h[0]), c = __half22float2(u5.h[1]);
                acc.x = fmaf(a.x, m5, acc.x); acc.y = fmaf(a.y, m5, acc.y);
                acc.z = fmaf(c.x, m5, acc.z); acc.w = fmaf(c.y, m5, acc.w);
            }
            {
                const float2 a = __half22float2(u6.h[0]), c = __half22float2(u6.h[1]);
                acc.x = fmaf(a.x, m6, acc.x); acc.y = fmaf(a.y, m6, acc.y);
                acc.z = fmaf(c.x, m6, acc.z); acc.w = fmaf(c.y, m6, acc.w);
            }
            {
                const float2 a = __half22float2(u7.h[0]), c = __half22float2(u7.h[1]);
                acc.x = fmaf(a.x, m7, acc.x); acc.y = fmaf(a.y, m7, acc.y);
                acc.z = fmaf(c.x, m7, acc.z); acc.w = fmaf(c.y, m7, acc.w);
            }
        }
        // stash h row (one ds_write_b128 per group)
        *(float4*)&hs[wv][sub][q << 2] = acc;

        // ---- MLP, pair-batched: ONE heavy W read per kg serves 2 nodes -----
        // (+8 accum VGPRs only; unroll capped at 4 to stop the scheduler
        // pipelining all 16 iterations -- r14's spill cause). hs reads are
        // same-address broadcasts (cheap). mcnt is wave-uniform.
        const int left = nend - base;
        const int mcnt = left < 4 ? left : 4;
        const int n0 = lo + base;
        {
            float4 rA = {bf, 0.f, 0.f, 0.f}, rB = rA;
            #pragma unroll 4
            for (int kg = 0; kg < 16; ++kg) {
                const float4 w  = *(const float4*)&Wt2[kg * WGROUP + (lane << 2)];
                const float4 hA = *(const float4*)&hs[wv][0][kg << 2];  // broadcast
                const float4 hB = *(const float4*)&hs[wv][1][kg << 2];
                rA.x = fmaf(hA.x, w.x, rA.x); rA.y = fmaf(hA.y, w.y, rA.y);
                rA.z = fmaf(hA.z, w.z, rA.z); rA.w = fmaf(hA.w, w.w, rA.w);
                rB.x = fmaf(hB.x, w.x, rB.x); rB.y = fmaf(hB.y, w.y, rB.y);
                rB.z = fmaf(hB.z, w.z, rB.z); rB.w = fmaf(hB.w, w.w, rB.w);
            }
            if (n0 < N_NODES)
                out[(size_t)n0 * D + lane] = fast_tanh((rA.x + rA.y) + (rA.z + rA.w));
            if (1 < mcnt && n0 + 1 < N_NODES)
                out[(size_t)(n0 + 1) * D + lane] = fast_tanh((rB.x + rB.y) + (rB.z + rB.w));
        }
        if (2 < mcnt) {                  // wave-uniform: skip whole pair on tails
            float4 rC = {bf, 0.f, 0.f, 0.f}, rD = rC;
            #pragma unroll 4
            for (int kg = 0; kg < 16; ++kg) {
                const float4 w  = *(const float4*)&Wt2[kg * WGROUP + (lane << 2)];
                const float4 hC = *(const float4*)&hs[wv][2][kg << 2];  // broadcast
                const float4 hD = *(const float4*)&hs[wv][3][kg << 2];
                rC.x = fmaf(hC.x, w.x, rC.x); rC.y = fmaf(hC.y, w.y, rC.y);
                rC.z = fmaf(hC.z, w.z, rC.z); rC.w = fmaf(hC.w, w.w, rC.w);
                rD.x = fmaf(hD.x, w.x, rD.x); rD.y = fmaf(hD.y, w.y, rD.y);
                rD.z = fmaf(hD.z, w.z, rD.z); rD.w = fmaf(hD.w, w.w, rD.w);
            }
            if (n0 + 2 < N_NODES)
                out[(size_t)(n0 + 2) * D + lane] = fast_tanh((rC.x + rC.y) + (rC.z + rC.w));
            if (3 < mcnt && n0 + 3 < N_NODES)
                out[(size_t)(n0 + 3) * D + lane] = fast_tanh((rD.x + rD.y) + (rD.z + rD.w));
        }
    }
}

extern "C" void kernel_launch(void* const* d_in, const int* in_sizes, int n_in,
                              void* d_out, int out_size, void* d_ws, size_t ws_size,
                              hipStream_t stream) {
    const float* x    = (const float*)d_in[0];   // [N, 64]
    const float* W    = (const float*)d_in[1];   // [64, 64] (PyTorch [out,in])
    const float* bias = (const float*)d_in[2];   // [64]
    const int*   src  = (const int*)d_in[3];     // [E] (int32 on device)
    const int*   dst  = (const int*)d_in[4];     // [E]
    float*       out  = (float*)d_out;           // [N, 64]

    // workspace: regions [160][512][26] u32 (8.52 MB) + bincnt [160][512]
    // (328 KB) + xh [N][64] fp16 (6.4 MB) = 15.3 MB. Nothing pre-cleared.
    unsigned int* regions = (unsigned int*)d_ws;
    int*          bincnt  = (int*)(regions + (size_t)PBLK * NBIN * CAPB);
    __half*       xh      = (__half*)(bincnt + PBLK * NBIN);

    gin_part<<<PBLK, 512, 0, stream>>>(x, src, dst, regions, bincnt, xh);
    gin_node<<<NBIN, 1024, 0, stream>>>(x, xh, W, bias, regions, bincnt, out);
}